// Round 14
// baseline (3927.126 us; speedup 1.0000x reference)
//
#include <hip/hip_runtime.h>
#include <stdint.h>

// BiLSTM B=32 T=2048 D=256 H=256 (gates i,f,g,o; c = f + c + i*g; h = o + tanh(c))
// R14 = R10 (best known: 16 WGs = dir x batch-quad, 1024 thr, 4 waves/SIMD,
//   wave-local gate tiles, one raw s_barrier/step, i8 MFMA) + exact fixes:
//   1) pre16 scatter slot = (hx + 5*l15)&15 -> all 8 bank-quads covered (was
//      2 quads / 8-way). Reads uniform 8 lanes/quad. Conflict-free both sides.
//   2) h i8 writes shfl-packed to dwords (R12's zero-conflict pattern).
//   3) y_net written DIRECTLY from k_rec (f32, fire-and-forget; raw barrier
//      never drains vmem) -> stage buffer + k_out kernel deleted.
//   4) fused sig(i)*sig(g) into one rcp. No setprio.

#define TT 2048

typedef __attribute__((ext_vector_type(8))) short  short8;
typedef __attribute__((ext_vector_type(8))) __bf16 bf16x8;
typedef __attribute__((ext_vector_type(4))) float  f32x4;
typedef __attribute__((ext_vector_type(4))) int    i32x4;

#define XW_BYTES (2ull*TT*32*1024*2)   // 256 MiB bf16 [d][t][b][hc*4+gate]

__device__ __forceinline__ unsigned short f2bf(float x){
  uint32_t u = __float_as_uint(x);
  return (unsigned short)((u + 0x7fffu + ((u>>16)&1u)) >> 16);
}
__device__ __forceinline__ float bf2f(unsigned short h){
  return __uint_as_float(((uint32_t)h)<<16);
}

// ---------------- Phase 1: x@W + b -> xw (bf16, [d][t][b][hc*4+gate]) --------
__global__ __launch_bounds__(512, 2)
void k_xw(const float* __restrict__ x, const float* __restrict__ Wf,
          const float* __restrict__ Wb, const float* __restrict__ bf,
          const float* __restrict__ bb, uint16_t* __restrict__ xw)
{
  __shared__ uint16_t wt[1024*32];  // 64 KiB
  const int bid = blockIdx.x;
  const int d   = bid >> 10;
  const int t0  = (bid & 1023) * 2;
  const float* __restrict__ W    = d ? Wb : Wf;
  const float* __restrict__ bias = d ? bb : bf;
  const int tid  = threadIdx.x;
  const int lane = tid & 63;
  const int wv   = tid >> 6;
  const int mt   = wv >> 1;
  const int nh   = wv & 1;
  const int l15  = lane & 15, lg = lane >> 4;

  f32x4 acc[32];
#pragma unroll
  for (int i=0;i<32;i++) acc[i] = (f32x4){0.f,0.f,0.f,0.f};

  const int arow = mt*16 + l15;
  const int ab   = arow & 31;
  const int atl  = arow >> 5;
  const float* __restrict__ xrow = x + ((size_t)ab*TT + (t0+atl))*256;

  for (int kc = 0; kc < 8; ++kc) {
    const int k0 = kc*32;
    __syncthreads();
#pragma unroll
    for (int cc=0; cc<2; ++cc){
      const int c = tid + cc*512;
      union { unsigned short s[32]; short8 v8[4]; } u;
#pragma unroll
      for (int j=0;j<32;j++) u.s[j] = f2bf(W[(size_t)(k0+j)*1024 + c]);
      short8* dst = (short8*)&wt[c*32];
#pragma unroll
      for (int o=0;o<4;o++) dst[o ^ (c&3)] = u.v8[o];
    }
    __syncthreads();
    union { unsigned short s[8]; short8 v; } af;
    {
      const float4 a0 = *(const float4*)&xrow[k0 + lg*8];
      const float4 a1 = *(const float4*)&xrow[k0 + lg*8 + 4];
      af.s[0]=f2bf(a0.x); af.s[1]=f2bf(a0.y); af.s[2]=f2bf(a0.z); af.s[3]=f2bf(a0.w);
      af.s[4]=f2bf(a1.x); af.s[5]=f2bf(a1.y); af.s[6]=f2bf(a1.z); af.s[7]=f2bf(a1.w);
    }
#pragma unroll
    for (int nt=0; nt<32; ++nt){
      const int ct = nh*512 + nt*16 + l15;
      short8 bfr = *(const short8*)&wt[ct*32 + ((lg ^ (ct&3))<<3)];
      acc[nt] = __builtin_amdgcn_mfma_f32_16x16x32_bf16(
        __builtin_bit_cast(bf16x8, af.v), __builtin_bit_cast(bf16x8, bfr), acc[nt], 0,0,0);
    }
  }
#pragma unroll
  for (int nt=0; nt<32; ++nt){
    const int c = nh*512 + nt*16 + l15;
    const int gate = c >> 8, hc = c & 255;
    const float bv = bias[c];
#pragma unroll
    for (int q=0;q<4;q++){
      const int row = mt*16 + lg*4 + q;
      const int b = row & 31, tl = row >> 5;
      xw[((size_t)(d*TT + t0 + tl)*32 + b)*1024 + hc*4 + gate] = f2bf(acc[nt][q] + bv);
    }
  }
}

// ---------------- Phase 2: recurrence, 16 WGs x 1024 thr (16 waves) ----------
__global__ __launch_bounds__(1024)
void k_rec(const float* __restrict__ Uf, const float* __restrict__ Ub,
           const uint16_t* __restrict__ xw, float* __restrict__ out)
{
  const int bid = blockIdx.x;           // 0..15
  const int d   = bid >> 3;
  const int bs  = bid & 7;
  const int tid  = threadIdx.x;
  const int lane = tid & 63;
  const int w    = tid >> 6;            // wave 0..15: hid cols [16w,16w+16)
  const int l15  = lane & 15, lg = lane >> 4;
  const int cb   = lane & 3;            // batch-in-quad
  const int hx   = lane >> 2;           // 0..15 hidden-col-in-wave
  const int gb   = bs*4 + cb;

  const float* __restrict__ U = d ? Ub : Uf;
  float* __restrict__ y_t   = out;
  float* __restrict__ y_net = out + 32*512;

  __shared__ i32x4 pre16[16*64];                          // 16 KB wave scratch
  __shared__ __align__(16) unsigned char hlds[2][1024];   // h i8 dbuf [b][hc]

  // A-frags resident: aU[q][m]; elem j -> U[k=m*64+lg*16+j][g=q*256+w*16+l15]
  i32x4 aU[4][4];
#pragma unroll
  for (int q=0;q<4;q++){
    const int g = q*256 + w*16 + l15;
#pragma unroll
    for (int m=0;m<4;m++){
      uint32_t rg[4] = {0,0,0,0};
#pragma unroll
      for (int jj=0;jj<16;jj++){
        const int k = m*64 + lg*16 + jj;
        float u = U[(size_t)k*1024 + g];
        int v = __float2int_rn(u * 2032.0f);              // 127/0.0625
        v = v > 127 ? 127 : (v < -127 ? -127 : v);
        rg[jj>>2] |= (uint32_t)(v & 255) << ((jj&3)*8);
      }
      aU[q][m] = (i32x4){(int)rg[0],(int)rg[1],(int)rg[2],(int)rg[3]};
    }
  }

  ((uint16_t*)hlds)[tid] = 0;           // zero both h buffers (2 KB)
  __syncthreads();

  const float DQ = 1.0f / (2032.0f * 63.5f);
  float cs = 0.f, hv = 0.f;

  const long xstep = (d ? -1 : 1) * (long)(32*1024);
  const long ystep = (d ? -1 : 1) * (long)(32*512);     // y_net t-stride (f32)
  const int tg0 = d ? TT-1 : 0;
  const uint16_t* px = xw + ((size_t)(d*TT + tg0)*32 + gb)*1024 + (w*16+hx)*4;
  float* py = y_net + ((size_t)gb*TT + tg0)*512 + d*256 + (w*16+hx);
  uint64_t gw0 = *(const uint64_t*)px; px += xstep;
  uint64_t gw1 = *(const uint64_t*)px; px += xstep;
  const long ystep2 = (d ? -1 : 1) * (long)512;         // per-t within batch row

  for (int t = 0; t < TT; ++t) {
    const int p = t & 1;

    // ---- MFMA: 16 insts, wave-local tiles (q, w); B = h broadcast (free) ----
    i32x4 acc[4];
#pragma unroll
    for (int q=0;q<4;q++) acc[q] = (i32x4){0,0,0,0};
    {
      const unsigned char* hb = &hlds[p][cb*256];
#pragma unroll
      for (int m=0;m<4;m++){
        i32x4 hf = *(const i32x4*)(hb + ((m*64 + lg*16) ^ (cb<<4)));
#pragma unroll
        for (int q=0;q<4;q++)
          acc[q] = __builtin_amdgcn_mfma_i32_16x16x64_i8(aU[q][m], hf, acc[q], 0,0,0);
      }
    }

    // ---- wave-local preact scatter, conflict-free slot = (hx + 5*l15)&15 ----
    if (l15 < 4){
#pragma unroll
      for (int r=0;r<4;r++){
        i32x4 v = (i32x4){acc[0][r], acc[1][r], acc[2][r], acc[3][r]};
        pre16[w*64 + l15*16 + ((lg*4 + r + 5*l15) & 15)] = v;
      }
    }
    asm volatile("s_waitcnt lgkmcnt(0)" ::: "memory");  // wave-local only
    __builtin_amdgcn_sched_barrier(0);

    // ---- gates: 1 cell/thread (cb, hc = w*16+hx); fused sig(i)*sig(g) ----
    i32x4 pv = pre16[w*64 + cb*16 + ((hx + 5*cb) & 15)];
    const uint64_t gwc = p ? gw1 : gw0;
    float pr[4];
#pragma unroll
    for (int q=0;q<4;q++)
      pr[q] = fmaf((float)pv[q], DQ, bf2f((unsigned short)(gwc >> (q*16))));
    float ea = __expf(-pr[0]);
    float eg = __expf(-pr[2]);
    float ig = __builtin_amdgcn_rcpf(1.0f + ea + eg + ea*eg);   // sig(i)*sig(g)
    float sf = __builtin_amdgcn_rcpf(1.0f + __expf(-pr[1]));
    float so = __builtin_amdgcn_rcpf(1.0f + __expf(-pr[3]));
    cs = sf + cs + ig;
    float th = 1.0f - 2.0f*__builtin_amdgcn_rcpf(1.0f + __expf(2.0f*cs));
    hv = so + th;                       // in (0,2)

    // ---- h -> i8; shfl-pack 4 hidden cols -> one dword LDS write ----
    int q8 = (int)(hv * 63.5f + 0.5f); q8 = q8 > 127 ? 127 : q8;
    uint32_t hq = (uint32_t)q8;
    uint32_t b1 = __shfl(hq, lane+4);
    uint32_t b2 = __shfl(hq, lane+8);
    uint32_t b3 = __shfl(hq, lane+12);
    if ((lane & 12) == 0)               // hx multiple of 4
      *(uint32_t*)&hlds[p^1][cb*256 + ((w*16 + hx) ^ (cb<<4))] =
          hq | (b1<<8) | (b2<<16) | (b3<<24);

    // ---- y_net f32 direct (fire-and-forget) + gw prefetch t+2 ----
    *py = hv; py += ystep2;
    if (p) gw1 = *(const uint64_t*)px; else gw0 = *(const uint64_t*)px;
    if (t < TT-3) px += xstep;

    // ---- step boundary: LDS visibility + raw barrier (NO vmcnt drain) ----
    asm volatile("s_waitcnt lgkmcnt(0)" ::: "memory");
    __builtin_amdgcn_sched_barrier(0);
    __builtin_amdgcn_s_barrier();
    __builtin_amdgcn_sched_barrier(0);
  }

  // ---- y_t (final h, f32) ----
  y_t[(size_t)gb*512 + d*256 + w*16 + hx] = hv;
}

extern "C" void kernel_launch(void* const* d_in, const int* in_sizes, int n_in,
                              void* d_out, int out_size, void* d_ws, size_t ws_size,
                              hipStream_t stream)
{
  const float* x  = (const float*)d_in[0];
  const float* Wf = (const float*)d_in[1];
  const float* Uf = (const float*)d_in[2];
  const float* bf = (const float*)d_in[3];
  const float* Wb = (const float*)d_in[4];
  const float* Ub = (const float*)d_in[5];
  const float* bb = (const float*)d_in[6];
  float* out = (float*)d_out;
  uint8_t* ws = (uint8_t*)d_ws;
  uint16_t* xw = (uint16_t*)ws;

  k_xw <<<dim3(2048), dim3(512),  0, stream>>>(x, Wf, Wb, bf, bb, xw);
  k_rec<<<dim3(16),   dim3(1024), 0, stream>>>(Uf, Ub, xw, out);
}

// Round 15
// 2593.277 us; speedup vs baseline: 1.5143x; 1.5143x over previous
//
#include <hip/hip_runtime.h>
#include <stdint.h>

// BiLSTM B=32 T=2048 D=256 H=256 (gates i,f,g,o; c = f + c + i*g; h = o + tanh(c))
// R15 = EXACT R10 (best measured: k_rec 2213us / total 2704us) + ONE change:
//   T5 dynamic s_setprio(1) around the per-step MFMA cluster. Mechanism: waves
//   alternate MFMA/gates roles each step; raising prio during the MFMA phase
//   lets the first waves through the barrier drain the matrix pipe early, then
//   run gates UNDER the later waves' MFMAs (role-split skew). R13's harmful
//   STATIC per-wave priorities are NOT used. Everything else byte-identical.

#define TT 2048

typedef __attribute__((ext_vector_type(8))) short  short8;
typedef __attribute__((ext_vector_type(8))) __bf16 bf16x8;
typedef __attribute__((ext_vector_type(4))) float  f32x4;
typedef __attribute__((ext_vector_type(4))) int    i32x4;

#define XW_BYTES    (2ull*TT*32*1024*2)     // 256 MiB bf16 [d][t][gb][hcol][gate]
#define STAGE_BYTES (2ull*TT*32*256*2)      // 64 MiB  bf16 [d][t][gb][hcol]

__device__ __forceinline__ unsigned short f2bf(float x){
  uint32_t u = __float_as_uint(x);
  return (unsigned short)((u + 0x7fffu + ((u>>16)&1u)) >> 16);
}
__device__ __forceinline__ float bf2f(unsigned short h){
  return __uint_as_float(((uint32_t)h)<<16);
}

// ---------------- Phase 1: x@W + b -> xw (bf16, [d][t][gb][hcol][gate]) --------
__global__ __launch_bounds__(512, 2)
void k_xw(const float* __restrict__ x, const float* __restrict__ Wf,
          const float* __restrict__ Wb, const float* __restrict__ bf,
          const float* __restrict__ bb, uint16_t* __restrict__ xw)
{
  __shared__ uint16_t wt[1024*32];  // 64 KiB
  const int bid = blockIdx.x;
  const int d   = bid >> 10;
  const int t0  = (bid & 1023) * 2;
  const float* __restrict__ W    = d ? Wb : Wf;
  const float* __restrict__ bias = d ? bb : bf;
  const int tid  = threadIdx.x;
  const int lane = tid & 63;
  const int wv   = tid >> 6;
  const int mt   = wv >> 1;
  const int nh   = wv & 1;
  const int l15  = lane & 15, lg = lane >> 4;

  f32x4 acc[32];
#pragma unroll
  for (int i=0;i<32;i++) acc[i] = (f32x4){0.f,0.f,0.f,0.f};

  const int arow = mt*16 + l15;
  const int ab   = arow & 31;
  const int atl  = arow >> 5;
  const float* __restrict__ xrow = x + ((size_t)ab*TT + (t0+atl))*256;

  for (int kc = 0; kc < 8; ++kc) {
    const int k0 = kc*32;
    __syncthreads();
#pragma unroll
    for (int cc=0; cc<2; ++cc){
      const int c = tid + cc*512;
      union { unsigned short s[32]; short8 v8[4]; } u;
#pragma unroll
      for (int j=0;j<32;j++) u.s[j] = f2bf(W[(size_t)(k0+j)*1024 + c]);
      short8* dst = (short8*)&wt[c*32];
#pragma unroll
      for (int o=0;o<4;o++) dst[o ^ (c&3)] = u.v8[o];
    }
    __syncthreads();
    union { unsigned short s[8]; short8 v; } af;
    {
      const float4 a0 = *(const float4*)&xrow[k0 + lg*8];
      const float4 a1 = *(const float4*)&xrow[k0 + lg*8 + 4];
      af.s[0]=f2bf(a0.x); af.s[1]=f2bf(a0.y); af.s[2]=f2bf(a0.z); af.s[3]=f2bf(a0.w);
      af.s[4]=f2bf(a1.x); af.s[5]=f2bf(a1.y); af.s[6]=f2bf(a1.z); af.s[7]=f2bf(a1.w);
    }
#pragma unroll
    for (int nt=0; nt<32; ++nt){
      const int ct = nh*512 + nt*16 + l15;
      short8 bfr = *(const short8*)&wt[ct*32 + ((lg ^ (ct&3))<<3)];
      acc[nt] = __builtin_amdgcn_mfma_f32_16x16x32_bf16(
        __builtin_bit_cast(bf16x8, af.v), __builtin_bit_cast(bf16x8, bfr), acc[nt], 0,0,0);
    }
  }
#pragma unroll
  for (int nt=0; nt<32; ++nt){
    const int c = nh*512 + nt*16 + l15;
    const int gate = c >> 8, hc = c & 255;
    const float bv = bias[c];
#pragma unroll
    for (int q=0;q<4;q++){
      const int row = mt*16 + lg*4 + q;
      const int b = row & 31, tl = row >> 5;
      xw[((size_t)(d*TT + t0 + tl)*32 + b)*1024 + hc*4 + gate] = f2bf(acc[nt][q] + bv);
    }
  }
}

// ---------------- Phase 2: recurrence, 16 WGs x 1024 thr (16 waves) ----------
__global__ __launch_bounds__(1024)
void k_rec(const float* __restrict__ Uf, const float* __restrict__ Ub,
           const uint16_t* __restrict__ xw, uint16_t* __restrict__ stage,
           float* __restrict__ out)
{
  const int bid = blockIdx.x;           // 0..15
  const int d   = bid >> 3;
  const int bs  = bid & 7;
  const int tid  = threadIdx.x;
  const int lane = tid & 63;
  const int w    = tid >> 6;            // wave 0..15
  const int l15  = lane & 15, lg = lane >> 4;
  const int cb   = lane & 3;            // batch-in-quad (B-read row / gates batch)
  const int hx   = lane >> 2;           // 0..15: hidden-col-in-wave (gates)
  const int gb   = bs*4 + cb;

  const float* __restrict__ U = d ? Ub : Uf;

  __shared__ i32x4 pre16[16*64];                          // 16 KB wave scratch
  __shared__ __align__(16) unsigned char hlds[2][1024];   // h i8 dbuf

  // A-frags resident: aU[q][m], tile (gate q, col-block w).
  // elem j: U[k = m*64 + lg*16 + j][g = q*256 + w*16 + l15]
  i32x4 aU[4][4];
#pragma unroll
  for (int q=0;q<4;q++){
    const int g = q*256 + w*16 + l15;
#pragma unroll
    for (int m=0;m<4;m++){
      uint32_t rg[4] = {0,0,0,0};
#pragma unroll
      for (int jj=0;jj<16;jj++){
        const int k = m*64 + lg*16 + jj;
        float u = U[(size_t)k*1024 + g];
        int v = __float2int_rn(u * 2032.0f);              // 127/0.0625
        v = v > 127 ? 127 : (v < -127 ? -127 : v);
        rg[jj>>2] |= (uint32_t)(v & 255) << ((jj&3)*8);
      }
      aU[q][m] = (i32x4){(int)rg[0],(int)rg[1],(int)rg[2],(int)rg[3]};
    }
  }

  ((uint16_t*)hlds)[tid] = 0;           // zero both h buffers (2 KB)
  __syncthreads();

  const float DQ = 1.0f / (2032.0f * 63.5f);
  float cs = 0.f, hcur = 0.f;

  auto gwload = [&](int t)->uint64_t {
    int tt = t < TT ? t : TT-1;
    int tg = d ? (TT-1-tt) : tt;
    return *(const uint64_t*)(xw + (((size_t)(d*TT + tg)*32 + gb)<<10) + (w*16+hx)*4);
  };
  uint64_t gw0 = gwload(0), gw1 = gwload(1);

  for (int t = 0; t < TT; t += 2) {
#pragma unroll
    for (int half = 0; half < 2; ++half) {
      const int tc  = t + half;
      const int pin = half;             // read hlds[pin], write hlds[pin^1]

      // ---- MFMA: 16 insts, wave-local tiles (q, w) — T5 prio window ----
      __builtin_amdgcn_s_setprio(1);
      i32x4 acc[4];
#pragma unroll
      for (int q=0;q<4;q++) acc[q] = (i32x4){0,0,0,0};
      {
        const unsigned char* hb = &hlds[pin][cb*256];
#pragma unroll
        for (int m=0;m<4;m++){
          i32x4 hf = *(const i32x4*)(hb + ((m*64 + lg*16) ^ (cb<<4)));
#pragma unroll
          for (int q=0;q<4;q++)
            acc[q] = __builtin_amdgcn_mfma_i32_16x16x64_i8(aU[q][m], hf, acc[q], 0,0,0);
        }
      }
      __builtin_amdgcn_s_setprio(0);

      // ---- wave-local preact scatter (q-packed i32x4) ----
      if (l15 < 4){
#pragma unroll
        for (int r=0;r<4;r++){
          i32x4 v = (i32x4){acc[0][r], acc[1][r], acc[2][r], acc[3][r]};
          pre16[w*64 + l15*16 + ((lg*4 + r + 2*l15) & 15)] = v;
        }
      }
      asm volatile("s_waitcnt lgkmcnt(0)" ::: "memory");  // wave-local only
      __builtin_amdgcn_sched_barrier(0);

      // ---- gates: 1 cell/thread (cb, hc = w*16+hx) ----
      i32x4 pv = pre16[w*64 + cb*16 + ((hx + 2*cb) & 15)];
      const uint64_t gwc = half ? gw1 : gw0;
      float pr[4];
#pragma unroll
      for (int q=0;q<4;q++)
        pr[q] = (float)pv[q]*DQ + bf2f((unsigned short)(gwc >> (q*16)));
      float si = __builtin_amdgcn_rcpf(1.0f + __expf(-pr[0]));
      float sf = __builtin_amdgcn_rcpf(1.0f + __expf(-pr[1]));
      float sg = __builtin_amdgcn_rcpf(1.0f + __expf(-pr[2]));
      float so = __builtin_amdgcn_rcpf(1.0f + __expf(-pr[3]));
      cs = sf + cs + si*sg;
      float th = 1.0f - 2.0f*__builtin_amdgcn_rcpf(1.0f + __expf(2.0f*cs));
      hcur = so + th;                   // in (0,2)

      // ---- h -> i8 byte to LDS buf pin^1 (swizzle matches B-frag read) ----
      int q8 = (int)(hcur * 63.5f + 0.5f); q8 = q8 > 127 ? 127 : q8;
      hlds[pin^1][cb*256 + ((w*16 + hx) ^ (cb<<4))] = (unsigned char)q8;

      // ---- stage (bf16, fire-and-forget; not drained by raw barrier) ----
      {
        const int tg = d ? (TT-1-tc) : tc;
        stage[(((size_t)(d*TT + tg)*32 + gb)<<8) + w*16 + hx] = f2bf(hcur);
      }
      // ---- gw prefetch for tc+2 (stays in flight) ----
      if (half) gw1 = gwload(tc+2); else gw0 = gwload(tc+2);

      // ---- step boundary: LDS visibility + raw barrier (NO vmcnt drain) ----
      asm volatile("s_waitcnt lgkmcnt(0)" ::: "memory");
      __builtin_amdgcn_sched_barrier(0);
      __builtin_amdgcn_s_barrier();
      __builtin_amdgcn_sched_barrier(0);
    }
  }

  // ---- y_t (final h, f32) ----
  out[(size_t)gb*512 + d*256 + w*16 + hx] = hcur;
}

// ---------------- Phase 3: stage -> y_net expand ----------------
__global__ __launch_bounds__(256)
void k_out(const uint16_t* __restrict__ stage, float* __restrict__ y_net)
{
  const int blk = blockIdx.x;
  const int b = blk >> 11;
  const int t = blk & 2047;
  const int tid = threadIdx.x;
  const uint16_t v0 = stage[((size_t)(0*TT + t)*32 + b)*256 + tid];
  const uint16_t v1 = stage[((size_t)(1*TT + t)*32 + b)*256 + tid];
  float* o = y_net + ((size_t)b*TT + t)*512;
  o[tid]       = bf2f(v0);
  o[tid + 256] = bf2f(v1);
}

extern "C" void kernel_launch(void* const* d_in, const int* in_sizes, int n_in,
                              void* d_out, int out_size, void* d_ws, size_t ws_size,
                              hipStream_t stream)
{
  const float* x  = (const float*)d_in[0];
  const float* Wf = (const float*)d_in[1];
  const float* Uf = (const float*)d_in[2];
  const float* bf = (const float*)d_in[3];
  const float* Wb = (const float*)d_in[4];
  const float* Ub = (const float*)d_in[5];
  const float* bb = (const float*)d_in[6];
  float* out = (float*)d_out;
  uint8_t* ws = (uint8_t*)d_ws;
  uint16_t* xw    = (uint16_t*)ws;
  uint16_t* stage = (uint16_t*)(ws + XW_BYTES);

  k_xw <<<dim3(2048),    dim3(512),  0, stream>>>(x, Wf, Wb, bf, bb, xw);
  k_rec<<<dim3(16),      dim3(1024), 0, stream>>>(Uf, Ub, xw, stage, out);
  k_out<<<dim3(32*2048), dim3(256),  0, stream>>>(stage, out + 32*512);
}

// Round 16
// 2392.150 us; speedup vs baseline: 1.6417x; 1.0841x over previous
//
#include <hip/hip_runtime.h>
#include <stdint.h>

// BiLSTM B=32 T=2048 D=256 H=256 (gates i,f,g,o; c = f + c + i*g; h = o + tanh(c))
// R16 = R15 (best: 2593us; k_rec+T5 setprio untouched) + ONE change in k_xw:
//   k_wq pre-converts W -> bf16 in the exact LDS-staging layout [d][kc][c][32k]
//   (1 MB, L2-resident). k_xw staging: 64 scalar dword loads + 64 f2bf per
//   thread per kc  ->  8 dwordx4 loads + same swizzled LDS writes. Epilogue,
//   MFMA loop, k_rec, k_out byte-identical to R15 (xw bit-identical).

#define TT 2048

typedef __attribute__((ext_vector_type(8))) short  short8;
typedef __attribute__((ext_vector_type(8))) __bf16 bf16x8;
typedef __attribute__((ext_vector_type(4))) float  f32x4;
typedef __attribute__((ext_vector_type(4))) int    i32x4;

#define XW_BYTES    (2ull*TT*32*1024*2)     // 256 MiB bf16 [d][t][gb][hcol][gate]
#define STAGE_BYTES (2ull*TT*32*256*2)      // 64 MiB  bf16 [d][t][gb][hcol]
#define WBF_BYTES   (2ull*8*1024*32*2)      // 1 MiB   bf16 [d][kc][c][32k]

__device__ __forceinline__ unsigned short f2bf(float x){
  uint32_t u = __float_as_uint(x);
  return (unsigned short)((u + 0x7fffu + ((u>>16)&1u)) >> 16);
}
__device__ __forceinline__ float bf2f(unsigned short h){
  return __uint_as_float(((uint32_t)h)<<16);
}

// ---------------- Phase 0: W f32 [k][c] -> wbf bf16 [d][kc][c][32k] ----------
__global__ __launch_bounds__(256)
void k_wq(const float* __restrict__ Wf, const float* __restrict__ Wb,
          uint16_t* __restrict__ wbf)
{
  const int blk = blockIdx.x;           // 64 blocks: (d*8+kc)*4 + cq
  const int dk  = blk >> 2;             // d*8+kc
  const int c   = (blk & 3)*256 + threadIdx.x;
  const int d   = dk >> 3, kc = dk & 7;
  const float* __restrict__ W = d ? Wb : Wf;
  uint16_t* dst = wbf + ((size_t)dk*1024 + c)*32;
#pragma unroll
  for (int j=0;j<32;j++)
    dst[j] = f2bf(W[(size_t)(kc*32 + j)*1024 + c]);
}

// ---------------- Phase 1: x@W + b -> xw (bf16, [d][t][gb][hcol][gate]) --------
__global__ __launch_bounds__(512, 2)
void k_xw(const float* __restrict__ x, const uint16_t* __restrict__ wbf,
          const float* __restrict__ bf, const float* __restrict__ bb,
          uint16_t* __restrict__ xw)
{
  __shared__ uint16_t wt[1024*32];  // 64 KiB
  const int bid = blockIdx.x;
  const int d   = bid >> 10;
  const int t0  = (bid & 1023) * 2;
  const float* __restrict__ bias = d ? bb : bf;
  const int tid  = threadIdx.x;
  const int lane = tid & 63;
  const int wv   = tid >> 6;
  const int mt   = wv >> 1;
  const int nh   = wv & 1;
  const int l15  = lane & 15, lg = lane >> 4;

  f32x4 acc[32];
#pragma unroll
  for (int i=0;i<32;i++) acc[i] = (f32x4){0.f,0.f,0.f,0.f};

  const int arow = mt*16 + l15;
  const int ab   = arow & 31;
  const int atl  = arow >> 5;
  const float* __restrict__ xrow = x + ((size_t)ab*TT + (t0+atl))*256;

  for (int kc = 0; kc < 8; ++kc) {
    const int k0 = kc*32;
    __syncthreads();
    // stage W chunk: pre-converted bf16, contiguous 64B per col
#pragma unroll
    for (int cc=0; cc<2; ++cc){
      const int c = tid + cc*512;
      const short8* wsrc = (const short8*)(wbf + ((size_t)(d*8 + kc)*1024 + c)*32);
      short8* dst = (short8*)&wt[c*32];
#pragma unroll
      for (int o=0;o<4;o++) dst[o ^ (c&3)] = wsrc[o];
    }
    __syncthreads();
    union { unsigned short s[8]; short8 v; } af;
    {
      const float4 a0 = *(const float4*)&xrow[k0 + lg*8];
      const float4 a1 = *(const float4*)&xrow[k0 + lg*8 + 4];
      af.s[0]=f2bf(a0.x); af.s[1]=f2bf(a0.y); af.s[2]=f2bf(a0.z); af.s[3]=f2bf(a0.w);
      af.s[4]=f2bf(a1.x); af.s[5]=f2bf(a1.y); af.s[6]=f2bf(a1.z); af.s[7]=f2bf(a1.w);
    }
#pragma unroll
    for (int nt=0; nt<32; ++nt){
      const int ct = nh*512 + nt*16 + l15;
      short8 bfr = *(const short8*)&wt[ct*32 + ((lg ^ (ct&3))<<3)];
      acc[nt] = __builtin_amdgcn_mfma_f32_16x16x32_bf16(
        __builtin_bit_cast(bf16x8, af.v), __builtin_bit_cast(bf16x8, bfr), acc[nt], 0,0,0);
    }
  }
#pragma unroll
  for (int nt=0; nt<32; ++nt){
    const int c = nh*512 + nt*16 + l15;
    const int gate = c >> 8, hc = c & 255;
    const float bv = bias[c];
#pragma unroll
    for (int q=0;q<4;q++){
      const int row = mt*16 + lg*4 + q;
      const int b = row & 31, tl = row >> 5;
      xw[((size_t)(d*TT + t0 + tl)*32 + b)*1024 + hc*4 + gate] = f2bf(acc[nt][q] + bv);
    }
  }
}

// ---------------- Phase 2: recurrence, 16 WGs x 1024 thr (16 waves) ----------
__global__ __launch_bounds__(1024)
void k_rec(const float* __restrict__ Uf, const float* __restrict__ Ub,
           const uint16_t* __restrict__ xw, uint16_t* __restrict__ stage,
           float* __restrict__ out)
{
  const int bid = blockIdx.x;           // 0..15
  const int d   = bid >> 3;
  const int bs  = bid & 7;
  const int tid  = threadIdx.x;
  const int lane = tid & 63;
  const int w    = tid >> 6;            // wave 0..15
  const int l15  = lane & 15, lg = lane >> 4;
  const int cb   = lane & 3;            // batch-in-quad (B-read row / gates batch)
  const int hx   = lane >> 2;           // 0..15: hidden-col-in-wave (gates)
  const int gb   = bs*4 + cb;

  const float* __restrict__ U = d ? Ub : Uf;

  __shared__ i32x4 pre16[16*64];                          // 16 KB wave scratch
  __shared__ __align__(16) unsigned char hlds[2][1024];   // h i8 dbuf

  // A-frags resident: aU[q][m], tile (gate q, col-block w).
  i32x4 aU[4][4];
#pragma unroll
  for (int q=0;q<4;q++){
    const int g = q*256 + w*16 + l15;
#pragma unroll
    for (int m=0;m<4;m++){
      uint32_t rg[4] = {0,0,0,0};
#pragma unroll
      for (int jj=0;jj<16;jj++){
        const int k = m*64 + lg*16 + jj;
        float u = U[(size_t)k*1024 + g];
        int v = __float2int_rn(u * 2032.0f);              // 127/0.0625
        v = v > 127 ? 127 : (v < -127 ? -127 : v);
        rg[jj>>2] |= (uint32_t)(v & 255) << ((jj&3)*8);
      }
      aU[q][m] = (i32x4){(int)rg[0],(int)rg[1],(int)rg[2],(int)rg[3]};
    }
  }

  ((uint16_t*)hlds)[tid] = 0;           // zero both h buffers (2 KB)
  __syncthreads();

  const float DQ = 1.0f / (2032.0f * 63.5f);
  float cs = 0.f, hcur = 0.f;

  auto gwload = [&](int t)->uint64_t {
    int tt = t < TT ? t : TT-1;
    int tg = d ? (TT-1-tt) : tt;
    return *(const uint64_t*)(xw + (((size_t)(d*TT + tg)*32 + gb)<<10) + (w*16+hx)*4);
  };
  uint64_t gw0 = gwload(0), gw1 = gwload(1);

  for (int t = 0; t < TT; t += 2) {
#pragma unroll
    for (int half = 0; half < 2; ++half) {
      const int tc  = t + half;
      const int pin = half;             // read hlds[pin], write hlds[pin^1]

      // ---- MFMA: 16 insts, wave-local tiles (q, w) — T5 prio window ----
      __builtin_amdgcn_s_setprio(1);
      i32x4 acc[4];
#pragma unroll
      for (int q=0;q<4;q++) acc[q] = (i32x4){0,0,0,0};
      {
        const unsigned char* hb = &hlds[pin][cb*256];
#pragma unroll
        for (int m=0;m<4;m++){
          i32x4 hf = *(const i32x4*)(hb + ((m*64 + lg*16) ^ (cb<<4)));
#pragma unroll
          for (int q=0;q<4;q++)
            acc[q] = __builtin_amdgcn_mfma_i32_16x16x64_i8(aU[q][m], hf, acc[q], 0,0,0);
        }
      }
      __builtin_amdgcn_s_setprio(0);

      // ---- wave-local preact scatter (q-packed i32x4) ----
      if (l15 < 4){
#pragma unroll
        for (int r=0;r<4;r++){
          i32x4 v = (i32x4){acc[0][r], acc[1][r], acc[2][r], acc[3][r]};
          pre16[w*64 + l15*16 + ((lg*4 + r + 2*l15) & 15)] = v;
        }
      }
      asm volatile("s_waitcnt lgkmcnt(0)" ::: "memory");  // wave-local only
      __builtin_amdgcn_sched_barrier(0);

      // ---- gates: 1 cell/thread (cb, hc = w*16+hx) ----
      i32x4 pv = pre16[w*64 + cb*16 + ((hx + 2*cb) & 15)];
      const uint64_t gwc = half ? gw1 : gw0;
      float pr[4];
#pragma unroll
      for (int q=0;q<4;q++)
        pr[q] = (float)pv[q]*DQ + bf2f((unsigned short)(gwc >> (q*16)));
      float si = __builtin_amdgcn_rcpf(1.0f + __expf(-pr[0]));
      float sf = __builtin_amdgcn_rcpf(1.0f + __expf(-pr[1]));
      float sg = __builtin_amdgcn_rcpf(1.0f + __expf(-pr[2]));
      float so = __builtin_amdgcn_rcpf(1.0f + __expf(-pr[3]));
      cs = sf + cs + si*sg;
      float th = 1.0f - 2.0f*__builtin_amdgcn_rcpf(1.0f + __expf(2.0f*cs));
      hcur = so + th;                   // in (0,2)

      // ---- h -> i8 byte to LDS buf pin^1 (swizzle matches B-frag read) ----
      int q8 = (int)(hcur * 63.5f + 0.5f); q8 = q8 > 127 ? 127 : q8;
      hlds[pin^1][cb*256 + ((w*16 + hx) ^ (cb<<4))] = (unsigned char)q8;

      // ---- stage (bf16, fire-and-forget; not drained by raw barrier) ----
      {
        const int tg = d ? (TT-1-tc) : tc;
        stage[(((size_t)(d*TT + tg)*32 + gb)<<8) + w*16 + hx] = f2bf(hcur);
      }
      // ---- gw prefetch for tc+2 (stays in flight) ----
      if (half) gw1 = gwload(tc+2); else gw0 = gwload(tc+2);

      // ---- step boundary: LDS visibility + raw barrier (NO vmcnt drain) ----
      asm volatile("s_waitcnt lgkmcnt(0)" ::: "memory");
      __builtin_amdgcn_sched_barrier(0);
      __builtin_amdgcn_s_barrier();
      __builtin_amdgcn_sched_barrier(0);
    }
  }

  // ---- y_t (final h, f32) ----
  out[(size_t)gb*512 + d*256 + w*16 + hx] = hcur;
}

// ---------------- Phase 3: stage -> y_net expand ----------------
__global__ __launch_bounds__(256)
void k_out(const uint16_t* __restrict__ stage, float* __restrict__ y_net)
{
  const int blk = blockIdx.x;
  const int b = blk >> 11;
  const int t = blk & 2047;
  const int tid = threadIdx.x;
  const uint16_t v0 = stage[((size_t)(0*TT + t)*32 + b)*256 + tid];
  const uint16_t v1 = stage[((size_t)(1*TT + t)*32 + b)*256 + tid];
  float* o = y_net + ((size_t)b*TT + t)*512;
  o[tid]       = bf2f(v0);
  o[tid + 256] = bf2f(v1);
}

extern "C" void kernel_launch(void* const* d_in, const int* in_sizes, int n_in,
                              void* d_out, int out_size, void* d_ws, size_t ws_size,
                              hipStream_t stream)
{
  const float* x  = (const float*)d_in[0];
  const float* Wf = (const float*)d_in[1];
  const float* Uf = (const float*)d_in[2];
  const float* bf = (const float*)d_in[3];
  const float* Wb = (const float*)d_in[4];
  const float* Ub = (const float*)d_in[5];
  const float* bb = (const float*)d_in[6];
  float* out = (float*)d_out;
  uint8_t* ws = (uint8_t*)d_ws;
  uint16_t* xw    = (uint16_t*)ws;
  uint16_t* stage = (uint16_t*)(ws + XW_BYTES);
  uint16_t* wbf   = (uint16_t*)(ws + XW_BYTES + STAGE_BYTES);

  k_wq <<<dim3(64),      dim3(256),  0, stream>>>(Wf, Wb, wbf);
  k_xw <<<dim3(2048),    dim3(512),  0, stream>>>(x, wbf, bf, bb, xw);
  k_rec<<<dim3(16),      dim3(1024), 0, stream>>>(Uf, Ub, xw, stage, out);
  k_out<<<dim3(32*2048), dim3(256),  0, stream>>>(stage, out + 32*512);
}

// Round 17
// 2323.264 us; speedup vs baseline: 1.6903x; 1.0297x over previous
//
#include <hip/hip_runtime.h>
#include <stdint.h>

// BiLSTM B=32 T=2048 D=256 H=256 (gates i,f,g,o; c = f + c + i*g; h = o + tanh(c))
// R17 = R16 (best: 2392us) + ONE change: h-buffer block swizzle cb<<4 ->
//   f(cb)<<4 with f(cb)=cb|((cb&1)<<2) in {0,5,2,7}. The B-frag ds_read_b128
//   quad = ((m*4+lg)^cb)&7 covered only 4/8 bank-quads (4-way distinct-addr
//   conflict, ~256 cy/WG-step = the measured 10.49M counter). f spans bit 2 ->
//   all 8 quads covered 2x (free). Applied at h byte-store AND B-frag read:
//   pure storage permutation, math bit-identical. Everything else = R16.

#define TT 2048

typedef __attribute__((ext_vector_type(8))) short  short8;
typedef __attribute__((ext_vector_type(8))) __bf16 bf16x8;
typedef __attribute__((ext_vector_type(4))) float  f32x4;
typedef __attribute__((ext_vector_type(4))) int    i32x4;

#define XW_BYTES    (2ull*TT*32*1024*2)     // 256 MiB bf16 [d][t][gb][hcol][gate]
#define STAGE_BYTES (2ull*TT*32*256*2)      // 64 MiB  bf16 [d][t][gb][hcol]
#define WBF_BYTES   (2ull*8*1024*32*2)      // 1 MiB   bf16 [d][kc][c][32k]

__device__ __forceinline__ unsigned short f2bf(float x){
  uint32_t u = __float_as_uint(x);
  return (unsigned short)((u + 0x7fffu + ((u>>16)&1u)) >> 16);
}
__device__ __forceinline__ float bf2f(unsigned short h){
  return __uint_as_float(((uint32_t)h)<<16);
}

// ---------------- Phase 0: W f32 [k][c] -> wbf bf16 [d][kc][c][32k] ----------
__global__ __launch_bounds__(256)
void k_wq(const float* __restrict__ Wf, const float* __restrict__ Wb,
          uint16_t* __restrict__ wbf)
{
  const int blk = blockIdx.x;           // 64 blocks: (d*8+kc)*4 + cq
  const int dk  = blk >> 2;             // d*8+kc
  const int c   = (blk & 3)*256 + threadIdx.x;
  const int d   = dk >> 3, kc = dk & 7;
  const float* __restrict__ W = d ? Wb : Wf;
  uint16_t* dst = wbf + ((size_t)dk*1024 + c)*32;
#pragma unroll
  for (int j=0;j<32;j++)
    dst[j] = f2bf(W[(size_t)(kc*32 + j)*1024 + c]);
}

// ---------------- Phase 1: x@W + b -> xw (bf16, [d][t][gb][hcol][gate]) --------
__global__ __launch_bounds__(512, 2)
void k_xw(const float* __restrict__ x, const uint16_t* __restrict__ wbf,
          const float* __restrict__ bf, const float* __restrict__ bb,
          uint16_t* __restrict__ xw)
{
  __shared__ uint16_t wt[1024*32];  // 64 KiB
  const int bid = blockIdx.x;
  const int d   = bid >> 10;
  const int t0  = (bid & 1023) * 2;
  const float* __restrict__ bias = d ? bb : bf;
  const int tid  = threadIdx.x;
  const int lane = tid & 63;
  const int wv   = tid >> 6;
  const int mt   = wv >> 1;
  const int nh   = wv & 1;
  const int l15  = lane & 15, lg = lane >> 4;

  f32x4 acc[32];
#pragma unroll
  for (int i=0;i<32;i++) acc[i] = (f32x4){0.f,0.f,0.f,0.f};

  const int arow = mt*16 + l15;
  const int ab   = arow & 31;
  const int atl  = arow >> 5;
  const float* __restrict__ xrow = x + ((size_t)ab*TT + (t0+atl))*256;

  for (int kc = 0; kc < 8; ++kc) {
    const int k0 = kc*32;
    __syncthreads();
    // stage W chunk: pre-converted bf16, contiguous 64B per col
#pragma unroll
    for (int cc=0; cc<2; ++cc){
      const int c = tid + cc*512;
      const short8* wsrc = (const short8*)(wbf + ((size_t)(d*8 + kc)*1024 + c)*32);
      short8* dst = (short8*)&wt[c*32];
#pragma unroll
      for (int o=0;o<4;o++) dst[o ^ (c&3)] = wsrc[o];
    }
    __syncthreads();
    union { unsigned short s[8]; short8 v; } af;
    {
      const float4 a0 = *(const float4*)&xrow[k0 + lg*8];
      const float4 a1 = *(const float4*)&xrow[k0 + lg*8 + 4];
      af.s[0]=f2bf(a0.x); af.s[1]=f2bf(a0.y); af.s[2]=f2bf(a0.z); af.s[3]=f2bf(a0.w);
      af.s[4]=f2bf(a1.x); af.s[5]=f2bf(a1.y); af.s[6]=f2bf(a1.z); af.s[7]=f2bf(a1.w);
    }
#pragma unroll
    for (int nt=0; nt<32; ++nt){
      const int ct = nh*512 + nt*16 + l15;
      short8 bfr = *(const short8*)&wt[ct*32 + ((lg ^ (ct&3))<<3)];
      acc[nt] = __builtin_amdgcn_mfma_f32_16x16x32_bf16(
        __builtin_bit_cast(bf16x8, af.v), __builtin_bit_cast(bf16x8, bfr), acc[nt], 0,0,0);
    }
  }
#pragma unroll
  for (int nt=0; nt<32; ++nt){
    const int c = nh*512 + nt*16 + l15;
    const int gate = c >> 8, hc = c & 255;
    const float bv = bias[c];
#pragma unroll
    for (int q=0;q<4;q++){
      const int row = mt*16 + lg*4 + q;
      const int b = row & 31, tl = row >> 5;
      xw[((size_t)(d*TT + t0 + tl)*32 + b)*1024 + hc*4 + gate] = f2bf(acc[nt][q] + bv);
    }
  }
}

// ---------------- Phase 2: recurrence, 16 WGs x 1024 thr (16 waves) ----------
__global__ __launch_bounds__(1024)
void k_rec(const float* __restrict__ Uf, const float* __restrict__ Ub,
           const uint16_t* __restrict__ xw, uint16_t* __restrict__ stage,
           float* __restrict__ out)
{
  const int bid = blockIdx.x;           // 0..15
  const int d   = bid >> 3;
  const int bs  = bid & 7;
  const int tid  = threadIdx.x;
  const int lane = tid & 63;
  const int w    = tid >> 6;            // wave 0..15
  const int l15  = lane & 15, lg = lane >> 4;
  const int cb   = lane & 3;            // batch-in-quad (B-read row / gates batch)
  const int hx   = lane >> 2;           // 0..15: hidden-col-in-wave (gates)
  const int gb   = bs*4 + cb;
  const int fsw  = cb | ((cb & 1) << 2);   // {0,5,2,7}: 3-bit block swizzle

  const float* __restrict__ U = d ? Ub : Uf;

  __shared__ i32x4 pre16[16*64];                          // 16 KB wave scratch
  __shared__ __align__(16) unsigned char hlds[2][1024];   // h i8 dbuf

  // A-frags resident: aU[q][m], tile (gate q, col-block w).
  i32x4 aU[4][4];
#pragma unroll
  for (int q=0;q<4;q++){
    const int g = q*256 + w*16 + l15;
#pragma unroll
    for (int m=0;m<4;m++){
      uint32_t rg[4] = {0,0,0,0};
#pragma unroll
      for (int jj=0;jj<16;jj++){
        const int k = m*64 + lg*16 + jj;
        float u = U[(size_t)k*1024 + g];
        int v = __float2int_rn(u * 2032.0f);              // 127/0.0625
        v = v > 127 ? 127 : (v < -127 ? -127 : v);
        rg[jj>>2] |= (uint32_t)(v & 255) << ((jj&3)*8);
      }
      aU[q][m] = (i32x4){(int)rg[0],(int)rg[1],(int)rg[2],(int)rg[3]};
    }
  }

  ((uint16_t*)hlds)[tid] = 0;           // zero both h buffers (2 KB)
  __syncthreads();

  const float DQ = 1.0f / (2032.0f * 63.5f);
  float cs = 0.f, hcur = 0.f;

  auto gwload = [&](int t)->uint64_t {
    int tt = t < TT ? t : TT-1;
    int tg = d ? (TT-1-tt) : tt;
    return *(const uint64_t*)(xw + (((size_t)(d*TT + tg)*32 + gb)<<10) + (w*16+hx)*4);
  };
  uint64_t gw0 = gwload(0), gw1 = gwload(1);

  for (int t = 0; t < TT; t += 2) {
#pragma unroll
    for (int half = 0; half < 2; ++half) {
      const int tc  = t + half;
      const int pin = half;             // read hlds[pin], write hlds[pin^1]

      // ---- MFMA: 16 insts, wave-local tiles (q, w) — T5 prio window ----
      __builtin_amdgcn_s_setprio(1);
      i32x4 acc[4];
#pragma unroll
      for (int q=0;q<4;q++) acc[q] = (i32x4){0,0,0,0};
      {
        const unsigned char* hb = &hlds[pin][cb*256];
#pragma unroll
        for (int m=0;m<4;m++){
          i32x4 hf = *(const i32x4*)(hb + ((m*64 + lg*16) ^ (fsw<<4)));
#pragma unroll
          for (int q=0;q<4;q++)
            acc[q] = __builtin_amdgcn_mfma_i32_16x16x64_i8(aU[q][m], hf, acc[q], 0,0,0);
        }
      }
      __builtin_amdgcn_s_setprio(0);

      // ---- wave-local preact scatter (q-packed i32x4) ----
      if (l15 < 4){
#pragma unroll
        for (int r=0;r<4;r++){
          i32x4 v = (i32x4){acc[0][r], acc[1][r], acc[2][r], acc[3][r]};
          pre16[w*64 + l15*16 + ((lg*4 + r + 2*l15) & 15)] = v;
        }
      }
      asm volatile("s_waitcnt lgkmcnt(0)" ::: "memory");  // wave-local only
      __builtin_amdgcn_sched_barrier(0);

      // ---- gates: 1 cell/thread (cb, hc = w*16+hx) ----
      i32x4 pv = pre16[w*64 + cb*16 + ((hx + 2*cb) & 15)];
      const uint64_t gwc = half ? gw1 : gw0;
      float pr[4];
#pragma unroll
      for (int q=0;q<4;q++)
        pr[q] = (float)pv[q]*DQ + bf2f((unsigned short)(gwc >> (q*16)));
      float si = __builtin_amdgcn_rcpf(1.0f + __expf(-pr[0]));
      float sf = __builtin_amdgcn_rcpf(1.0f + __expf(-pr[1]));
      float sg = __builtin_amdgcn_rcpf(1.0f + __expf(-pr[2]));
      float so = __builtin_amdgcn_rcpf(1.0f + __expf(-pr[3]));
      cs = sf + cs + si*sg;
      float th = 1.0f - 2.0f*__builtin_amdgcn_rcpf(1.0f + __expf(2.0f*cs));
      hcur = so + th;                   // in (0,2)

      // ---- h -> i8 byte to LDS buf pin^1 (swizzle matches B-frag read) ----
      int q8 = (int)(hcur * 63.5f + 0.5f); q8 = q8 > 127 ? 127 : q8;
      hlds[pin^1][cb*256 + ((w*16 + hx) ^ (fsw<<4))] = (unsigned char)q8;

      // ---- stage (bf16, fire-and-forget; not drained by raw barrier) ----
      {
        const int tg = d ? (TT-1-tc) : tc;
        stage[(((size_t)(d*TT + tg)*32 + gb)<<8) + w*16 + hx] = f2bf(hcur);
      }
      // ---- gw prefetch for tc+2 (stays in flight) ----
      if (half) gw1 = gwload(tc+2); else gw0 = gwload(tc+2);

      // ---- step boundary: LDS visibility + raw barrier (NO vmcnt drain) ----
      asm volatile("s_waitcnt lgkmcnt(0)" ::: "memory");
      __builtin_amdgcn_sched_barrier(0);
      __builtin_amdgcn_s_barrier();
      __builtin_amdgcn_sched_barrier(0);
    }
  }

  // ---- y_t (final h, f32) ----
  out[(size_t)gb*512 + d*256 + w*16 + hx] = hcur;
}

// ---------------- Phase 3: stage -> y_net expand ----------------
__global__ __launch_bounds__(256)
void k_out(const uint16_t* __restrict__ stage, float* __restrict__ y_net)
{
  const int blk = blockIdx.x;
  const int b = blk >> 11;
  const int t = blk & 2047;
  const int tid = threadIdx.x;
  const uint16_t v0 = stage[((size_t)(0*TT + t)*32 + b)*256 + tid];
  const uint16_t v1 = stage[((size_t)(1*TT + t)*32 + b)*256 + tid];
  float* o = y_net + ((size_t)b*TT + t)*512;
  o[tid]       = bf2f(v0);
  o[tid + 256] = bf2f(v1);
}

extern "C" void kernel_launch(void* const* d_in, const int* in_sizes, int n_in,
                              void* d_out, int out_size, void* d_ws, size_t ws_size,
                              hipStream_t stream)
{
  const float* x  = (const float*)d_in[0];
  const float* Wf = (const float*)d_in[1];
  const float* Uf = (const float*)d_in[2];
  const float* bf = (const float*)d_in[3];
  const float* Wb = (const float*)d_in[4];
  const float* Ub = (const float*)d_in[5];
  const float* bb = (const float*)d_in[6];
  float* out = (float*)d_out;
  uint8_t* ws = (uint8_t*)d_ws;
  uint16_t* xw    = (uint16_t*)ws;
  uint16_t* stage = (uint16_t*)(ws + XW_BYTES);
  uint16_t* wbf   = (uint16_t*)(ws + XW_BYTES + STAGE_BYTES);

  k_wq <<<dim3(64),      dim3(256),  0, stream>>>(Wf, Wb, wbf);
  k_xw <<<dim3(2048),    dim3(512),  0, stream>>>(x, wbf, bf, bb, xw);
  k_rec<<<dim3(16),      dim3(1024), 0, stream>>>(Uf, Ub, xw, stage, out);
  k_out<<<dim3(32*2048), dim3(256),  0, stream>>>(stage, out + 32*512);
}

// Round 18
// 2263.824 us; speedup vs baseline: 1.7347x; 1.0263x over previous
//
#include <hip/hip_runtime.h>
#include <stdint.h>

// BiLSTM B=32 T=2048 D=256 H=256 (gates i,f,g,o; c = f + c + i*g; h = o + tanh(c))
// R18 = R17 (best: 2323us) + ONE change: k_rec writes y_net f32 DIRECTLY
//   (fire-and-forget; raw barrier never drains vmcnt -> same cost as the old
//   stage bf16 store), k_out pass + stage buffer deleted (~90us + 190MB HBM).
//   This is R14's change #3 isolated from the two LDS changes that confounded
//   it. k_rec math/LDS/swizzles/setprio byte-identical to R17.

#define TT 2048

typedef __attribute__((ext_vector_type(8))) short  short8;
typedef __attribute__((ext_vector_type(8))) __bf16 bf16x8;
typedef __attribute__((ext_vector_type(4))) float  f32x4;
typedef __attribute__((ext_vector_type(4))) int    i32x4;

#define XW_BYTES  (2ull*TT*32*1024*2)     // 256 MiB bf16 [d][t][gb][hcol][gate]
#define WBF_BYTES (2ull*8*1024*32*2)      // 1 MiB   bf16 [d][kc][c][32k]

__device__ __forceinline__ unsigned short f2bf(float x){
  uint32_t u = __float_as_uint(x);
  return (unsigned short)((u + 0x7fffu + ((u>>16)&1u)) >> 16);
}
__device__ __forceinline__ float bf2f(unsigned short h){
  return __uint_as_float(((uint32_t)h)<<16);
}

// ---------------- Phase 0: W f32 [k][c] -> wbf bf16 [d][kc][c][32k] ----------
__global__ __launch_bounds__(256)
void k_wq(const float* __restrict__ Wf, const float* __restrict__ Wb,
          uint16_t* __restrict__ wbf)
{
  const int blk = blockIdx.x;           // 64 blocks: (d*8+kc)*4 + cq
  const int dk  = blk >> 2;             // d*8+kc
  const int c   = (blk & 3)*256 + threadIdx.x;
  const int d   = dk >> 3, kc = dk & 7;
  const float* __restrict__ W = d ? Wb : Wf;
  uint16_t* dst = wbf + ((size_t)dk*1024 + c)*32;
#pragma unroll
  for (int j=0;j<32;j++)
    dst[j] = f2bf(W[(size_t)(kc*32 + j)*1024 + c]);
}

// ---------------- Phase 1: x@W + b -> xw (bf16, [d][t][gb][hcol][gate]) --------
__global__ __launch_bounds__(512, 2)
void k_xw(const float* __restrict__ x, const uint16_t* __restrict__ wbf,
          const float* __restrict__ bf, const float* __restrict__ bb,
          uint16_t* __restrict__ xw)
{
  __shared__ uint16_t wt[1024*32];  // 64 KiB
  const int bid = blockIdx.x;
  const int d   = bid >> 10;
  const int t0  = (bid & 1023) * 2;
  const float* __restrict__ bias = d ? bb : bf;
  const int tid  = threadIdx.x;
  const int lane = tid & 63;
  const int wv   = tid >> 6;
  const int mt   = wv >> 1;
  const int nh   = wv & 1;
  const int l15  = lane & 15, lg = lane >> 4;

  f32x4 acc[32];
#pragma unroll
  for (int i=0;i<32;i++) acc[i] = (f32x4){0.f,0.f,0.f,0.f};

  const int arow = mt*16 + l15;
  const int ab   = arow & 31;
  const int atl  = arow >> 5;
  const float* __restrict__ xrow = x + ((size_t)ab*TT + (t0+atl))*256;

  for (int kc = 0; kc < 8; ++kc) {
    const int k0 = kc*32;
    __syncthreads();
    // stage W chunk: pre-converted bf16, contiguous 64B per col
#pragma unroll
    for (int cc=0; cc<2; ++cc){
      const int c = tid + cc*512;
      const short8* wsrc = (const short8*)(wbf + ((size_t)(d*8 + kc)*1024 + c)*32);
      short8* dst = (short8*)&wt[c*32];
#pragma unroll
      for (int o=0;o<4;o++) dst[o ^ (c&3)] = wsrc[o];
    }
    __syncthreads();
    union { unsigned short s[8]; short8 v; } af;
    {
      const float4 a0 = *(const float4*)&xrow[k0 + lg*8];
      const float4 a1 = *(const float4*)&xrow[k0 + lg*8 + 4];
      af.s[0]=f2bf(a0.x); af.s[1]=f2bf(a0.y); af.s[2]=f2bf(a0.z); af.s[3]=f2bf(a0.w);
      af.s[4]=f2bf(a1.x); af.s[5]=f2bf(a1.y); af.s[6]=f2bf(a1.z); af.s[7]=f2bf(a1.w);
    }
#pragma unroll
    for (int nt=0; nt<32; ++nt){
      const int ct = nh*512 + nt*16 + l15;
      short8 bfr = *(const short8*)&wt[ct*32 + ((lg ^ (ct&3))<<3)];
      acc[nt] = __builtin_amdgcn_mfma_f32_16x16x32_bf16(
        __builtin_bit_cast(bf16x8, af.v), __builtin_bit_cast(bf16x8, bfr), acc[nt], 0,0,0);
    }
  }
#pragma unroll
  for (int nt=0; nt<32; ++nt){
    const int c = nh*512 + nt*16 + l15;
    const int gate = c >> 8, hc = c & 255;
    const float bv = bias[c];
#pragma unroll
    for (int q=0;q<4;q++){
      const int row = mt*16 + lg*4 + q;
      const int b = row & 31, tl = row >> 5;
      xw[((size_t)(d*TT + t0 + tl)*32 + b)*1024 + hc*4 + gate] = f2bf(acc[nt][q] + bv);
    }
  }
}

// ---------------- Phase 2: recurrence, 16 WGs x 1024 thr (16 waves) ----------
__global__ __launch_bounds__(1024)
void k_rec(const float* __restrict__ Uf, const float* __restrict__ Ub,
           const uint16_t* __restrict__ xw, float* __restrict__ out)
{
  const int bid = blockIdx.x;           // 0..15
  const int d   = bid >> 3;
  const int bs  = bid & 7;
  const int tid  = threadIdx.x;
  const int lane = tid & 63;
  const int w    = tid >> 6;            // wave 0..15
  const int l15  = lane & 15, lg = lane >> 4;
  const int cb   = lane & 3;            // batch-in-quad (B-read row / gates batch)
  const int hx   = lane >> 2;           // 0..15: hidden-col-in-wave (gates)
  const int gb   = bs*4 + cb;
  const int fsw  = cb | ((cb & 1) << 2);   // {0,5,2,7}: 3-bit block swizzle

  const float* __restrict__ U = d ? Ub : Uf;
  float* __restrict__ y_t   = out;
  float* __restrict__ y_net = out + 32*512;

  __shared__ i32x4 pre16[16*64];                          // 16 KB wave scratch
  __shared__ __align__(16) unsigned char hlds[2][1024];   // h i8 dbuf

  // A-frags resident: aU[q][m], tile (gate q, col-block w).
  i32x4 aU[4][4];
#pragma unroll
  for (int q=0;q<4;q++){
    const int g = q*256 + w*16 + l15;
#pragma unroll
    for (int m=0;m<4;m++){
      uint32_t rg[4] = {0,0,0,0};
#pragma unroll
      for (int jj=0;jj<16;jj++){
        const int k = m*64 + lg*16 + jj;
        float u = U[(size_t)k*1024 + g];
        int v = __float2int_rn(u * 2032.0f);              // 127/0.0625
        v = v > 127 ? 127 : (v < -127 ? -127 : v);
        rg[jj>>2] |= (uint32_t)(v & 255) << ((jj&3)*8);
      }
      aU[q][m] = (i32x4){(int)rg[0],(int)rg[1],(int)rg[2],(int)rg[3]};
    }
  }

  ((uint16_t*)hlds)[tid] = 0;           // zero both h buffers (2 KB)
  __syncthreads();

  const float DQ = 1.0f / (2032.0f * 63.5f);
  float cs = 0.f, hcur = 0.f;

  auto gwload = [&](int t)->uint64_t {
    int tt = t < TT ? t : TT-1;
    int tg = d ? (TT-1-tt) : tt;
    return *(const uint64_t*)(xw + (((size_t)(d*TT + tg)*32 + gb)<<10) + (w*16+hx)*4);
  };
  uint64_t gw0 = gwload(0), gw1 = gwload(1);

  // direct y_net pointer (walks t in this chain's time order)
  const int tg0 = d ? TT-1 : 0;
  const long ystep = (d ? -1 : 1) * (long)512;
  float* py = y_net + ((size_t)gb*TT + tg0)*512 + d*256 + w*16 + hx;

  for (int t = 0; t < TT; t += 2) {
#pragma unroll
    for (int half = 0; half < 2; ++half) {
      const int tc  = t + half;
      const int pin = half;             // read hlds[pin], write hlds[pin^1]

      // ---- MFMA: 16 insts, wave-local tiles (q, w) — T5 prio window ----
      __builtin_amdgcn_s_setprio(1);
      i32x4 acc[4];
#pragma unroll
      for (int q=0;q<4;q++) acc[q] = (i32x4){0,0,0,0};
      {
        const unsigned char* hb = &hlds[pin][cb*256];
#pragma unroll
        for (int m=0;m<4;m++){
          i32x4 hf = *(const i32x4*)(hb + ((m*64 + lg*16) ^ (fsw<<4)));
#pragma unroll
          for (int q=0;q<4;q++)
            acc[q] = __builtin_amdgcn_mfma_i32_16x16x64_i8(aU[q][m], hf, acc[q], 0,0,0);
        }
      }
      __builtin_amdgcn_s_setprio(0);

      // ---- wave-local preact scatter (q-packed i32x4) ----
      if (l15 < 4){
#pragma unroll
        for (int r=0;r<4;r++){
          i32x4 v = (i32x4){acc[0][r], acc[1][r], acc[2][r], acc[3][r]};
          pre16[w*64 + l15*16 + ((lg*4 + r + 2*l15) & 15)] = v;
        }
      }
      asm volatile("s_waitcnt lgkmcnt(0)" ::: "memory");  // wave-local only
      __builtin_amdgcn_sched_barrier(0);

      // ---- gates: 1 cell/thread (cb, hc = w*16+hx) ----
      i32x4 pv = pre16[w*64 + cb*16 + ((hx + 2*cb) & 15)];
      const uint64_t gwc = half ? gw1 : gw0;
      float pr[4];
#pragma unroll
      for (int q=0;q<4;q++)
        pr[q] = (float)pv[q]*DQ + bf2f((unsigned short)(gwc >> (q*16)));
      float si = __builtin_amdgcn_rcpf(1.0f + __expf(-pr[0]));
      float sf = __builtin_amdgcn_rcpf(1.0f + __expf(-pr[1]));
      float sg = __builtin_amdgcn_rcpf(1.0f + __expf(-pr[2]));
      float so = __builtin_amdgcn_rcpf(1.0f + __expf(-pr[3]));
      cs = sf + cs + si*sg;
      float th = 1.0f - 2.0f*__builtin_amdgcn_rcpf(1.0f + __expf(2.0f*cs));
      hcur = so + th;                   // in (0,2)

      // ---- h -> i8 byte to LDS buf pin^1 (swizzle matches B-frag read) ----
      int q8 = (int)(hcur * 63.5f + 0.5f); q8 = q8 > 127 ? 127 : q8;
      hlds[pin^1][cb*256 + ((w*16 + hx) ^ (fsw<<4))] = (unsigned char)q8;

      // ---- y_net f32 direct (fire-and-forget; not drained by raw barrier) ----
      *py = hcur; py += ystep;

      // ---- gw prefetch for tc+2 (stays in flight) ----
      if (half) gw1 = gwload(tc+2); else gw0 = gwload(tc+2);

      // ---- step boundary: LDS visibility + raw barrier (NO vmcnt drain) ----
      asm volatile("s_waitcnt lgkmcnt(0)" ::: "memory");
      __builtin_amdgcn_sched_barrier(0);
      __builtin_amdgcn_s_barrier();
      __builtin_amdgcn_sched_barrier(0);
    }
  }

  // ---- y_t (final h, f32) ----
  y_t[(size_t)gb*512 + d*256 + w*16 + hx] = hcur;
}

extern "C" void kernel_launch(void* const* d_in, const int* in_sizes, int n_in,
                              void* d_out, int out_size, void* d_ws, size_t ws_size,
                              hipStream_t stream)
{
  const float* x  = (const float*)d_in[0];
  const float* Wf = (const float*)d_in[1];
  const float* Uf = (const float*)d_in[2];
  const float* bf = (const float*)d_in[3];
  const float* Wb = (const float*)d_in[4];
  const float* Ub = (const float*)d_in[5];
  const float* bb = (const float*)d_in[6];
  float* out = (float*)d_out;
  uint8_t* ws = (uint8_t*)d_ws;
  uint16_t* xw  = (uint16_t*)ws;
  uint16_t* wbf = (uint16_t*)(ws + XW_BYTES);

  k_wq <<<dim3(64),   dim3(256),  0, stream>>>(Wf, Wb, wbf);
  k_xw <<<dim3(2048), dim3(512),  0, stream>>>(x, wbf, bf, bb, xw);
  k_rec<<<dim3(16),   dim3(1024), 0, stream>>>(Uf, Ub, xw, out);
}